// Round 1
// baseline (176.929 us; speedup 1.0000x reference)
//
#include <hip/hip_runtime.h>

typedef float  f32x4  __attribute__((ext_vector_type(4)));
typedef short  bf16x8 __attribute__((ext_vector_type(8)));
typedef short  bf16x4 __attribute__((ext_vector_type(4)));

#define NN 2048
#define CC 64

__device__ __forceinline__ unsigned short f2bf(float f) {
  union { float f; unsigned u; } v; v.f = f;
  unsigned r = v.u + 0x7fffu + ((v.u >> 16) & 1u);
  return (unsigned short)(r >> 16);
}

// ---------- per-layer small linear: Mt = (H*Wm^T)^T (bf16), S = H*Ws^T + b (fp32) ----------
__global__ __launch_bounds__(256) void gcn_linear(
    const float* __restrict__ H, const float* __restrict__ Wm,
    const float* __restrict__ Ws, const float* __restrict__ bias,
    unsigned short* __restrict__ Mt, float* __restrict__ S)
{
  const int bid = blockIdx.x;
  const int b   = bid >> 5;          // 32 row-blocks per batch
  const int n0  = (bid & 31) << 6;   // 64 rows per block
  const int tid = threadIdx.x;

  __shared__ float4 Hl[1024];    // [row][c4] 64x16 float4
  __shared__ float4 Wm4[1024];   // [o][c4 ^ (o&15)] swizzled
  __shared__ float4 Ws4[1024];

  const float4* Hg  = reinterpret_cast<const float4*>(H + ((size_t)b * NN + n0) * CC);
  const float4* Wmg = reinterpret_cast<const float4*>(Wm);
  const float4* Wsg = reinterpret_cast<const float4*>(Ws);
#pragma unroll
  for (int i = 0; i < 4; ++i) {
    int f = tid + 256 * i;
    Hl[f] = Hg[f];
    int o = f >> 4, c4 = f & 15;
    int slot = (o << 4) | (c4 ^ (o & 15));
    Wm4[slot] = Wmg[f];
    Ws4[slot] = Wsg[f];
  }
  __syncthreads();

  const int o = tid & 63, wv = tid >> 6;
  float accm[16], accs[16];
#pragma unroll
  for (int p = 0; p < 16; ++p) { accm[p] = 0.f; accs[p] = 0.f; }

  for (int c4 = 0; c4 < 16; ++c4) {
    int slot = (o << 4) | (c4 ^ (o & 15));
    float4 wm  = Wm4[slot];
    float4 wsv = Ws4[slot];
#pragma unroll
    for (int p = 0; p < 16; ++p) {
      float4 h = Hl[((wv << 4) + p) * 16 + c4];   // broadcast within wave
      accm[p] += h.x * wm.x  + h.y * wm.y  + h.z * wm.z  + h.w * wm.w;
      accs[p] += h.x * wsv.x + h.y * wsv.y + h.z * wsv.z + h.w * wsv.w;
    }
  }

  const float bv = bias[o];
#pragma unroll
  for (int p = 0; p < 16; ++p) {
    int r = n0 + (wv << 4) + p;
    Mt[((size_t)b * CC + o) * NN + r] = f2bf(accm[p]);   // transposed store (bf16)
    S [((size_t)b * NN + r) * CC + o] = accs[p] + bv;    // coalesced fp32
  }
}

// ---------- heavy GEMM: H = relu?(A @ M + S), A fp32 streamed -> bf16 MFMA ----------
__global__ __launch_bounds__(256) void gcn_gemm(
    const float* __restrict__ A, const unsigned short* __restrict__ Mt,
    const float* __restrict__ S, float* __restrict__ Hout, const int relu)
{
  const int bid = blockIdx.x;
  const int lg  = (bid & 7) * 32 + (bid >> 3);  // XCD-contiguous: each XCD owns one batch
  const int b   = lg >> 5;
  const int i0  = (lg & 31) << 6;

  const int tid  = threadIdx.x;
  const int lane = tid & 63;
  const int w    = tid >> 6;
  const int fr   = lane & 15;
  const int g    = lane >> 4;
  const int arow = (w << 4) | fr;

  __shared__ __align__(16) unsigned short Abuf[2][64 * 64]; // bf16, XOR-swizzled rows

  const float* Ab = A + (size_t)b * NN * NN + (size_t)i0 * NN;
  const unsigned short* Mb = Mt + (size_t)b * CC * NN;

  const int sr = tid >> 2;     // staging row 0..63
  const int sc = tid & 3;      // staging float4 lane-slot
  const float* arp = Ab + (size_t)sr * NN;

  f32x4 acc[4];
#pragma unroll
  for (int n = 0; n < 4; ++n) acc[n] = (f32x4){0.f, 0.f, 0.f, 0.f};

#define STAGE(PB, RG) do {                                                         \
    _Pragma("unroll")                                                              \
    for (int i_ = 0; i_ < 4; ++i_) {                                               \
      bf16x4 pk_;                                                                  \
      pk_[0] = (short)f2bf((RG)[i_].x);                                            \
      pk_[1] = (short)f2bf((RG)[i_].y);                                            \
      pk_[2] = (short)f2bf((RG)[i_].z);                                            \
      pk_[3] = (short)f2bf((RG)[i_].w);                                            \
      unsigned off_ = (unsigned)(sr * 128 + 8 * (sc + 4 * i_))                     \
                    ^ (unsigned)((sr & 7) << 4);                                   \
      *reinterpret_cast<bf16x4*>(reinterpret_cast<char*>(&Abuf[(PB)][0]) + off_) = pk_; \
    }                                                                              \
  } while (0)

  float4 regs[4];
#pragma unroll
  for (int i = 0; i < 4; ++i)
    regs[i] = *reinterpret_cast<const float4*>(arp + 4 * (sc + 4 * i));
  STAGE(0, regs);
  __syncthreads();

  int p = 0;
  for (int t = 0; t < 32; ++t) {
    float4 nregs[4];
    if (t < 31) {                     // prefetch next A-tile into registers
      const float* q = arp + (t + 1) * 64;
#pragma unroll
      for (int i = 0; i < 4; ++i)
        nregs[i] = *reinterpret_cast<const float4*>(q + 4 * (sc + 4 * i));
    }
    const int j0 = t << 6;
#pragma unroll
    for (int kk = 0; kk < 2; ++kk) {
      unsigned aoff = (unsigned)(arow * 128 + (kk << 6) + (g << 4))
                    ^ (unsigned)((arow & 7) << 4);
      bf16x8 af = *reinterpret_cast<bf16x8*>(reinterpret_cast<char*>(&Abuf[p][0]) + aoff);
#pragma unroll
      for (int n = 0; n < 4; ++n) {
        const unsigned short* mp = Mb + (size_t)((n << 4) | fr) * NN
                                      + (j0 + (kk << 5) + (g << 3));
        bf16x8 bf = *reinterpret_cast<const bf16x8*>(mp);  // L1/L2-resident 16B load
        acc[n] = __builtin_amdgcn_mfma_f32_16x16x32_bf16(af, bf, acc[n], 0, 0, 0);
      }
    }
    if (t < 31) STAGE(p ^ 1, nregs);  // write next tile to alternate buffer
    __syncthreads();
    p ^= 1;
  }
#undef STAGE

  // epilogue: C/D layout col=lane&15, row=(lane>>4)*4+reg  [measured m89/m91]
  const int rbase = i0 + (w << 4) + (g << 2);
#pragma unroll
  for (int n = 0; n < 4; ++n) {
    const int col = (n << 4) | fr;
#pragma unroll
    for (int r = 0; r < 4; ++r) {
      const size_t idx = ((size_t)b * NN + (rbase + r)) * CC + col;
      float v = acc[n][r] + S[idx];
      if (relu) v = fmaxf(v, 0.f);
      Hout[idx] = v;
    }
  }
}

extern "C" void kernel_launch(void* const* d_in, const int* in_sizes, int n_in,
                              void* d_out, int out_size, void* d_ws, size_t ws_size,
                              hipStream_t stream)
{
  const float* X = (const float*)d_in[0];
  const float* A = (const float*)d_in[1];
  unsigned short* Mt = (unsigned short*)d_ws;                       // 2 MiB bf16
  float* S = (float*)((char*)d_ws + (size_t)(2 * 1024 * 1024));     // 4 MiB fp32
  float* H = (float*)d_out;                                         // ping-pong activations

  for (int l = 0; l < 3; ++l) {
    const float* Wm = (const float*)d_in[2 + 3 * l];
    const float* Ws = (const float*)d_in[3 + 3 * l];
    const float* bb = (const float*)d_in[4 + 3 * l];
    const float* src = (l == 0) ? X : H;
    gcn_linear<<<dim3(256), dim3(256), 0, stream>>>(src, Wm, Ws, bb, Mt, S);
    gcn_gemm  <<<dim3(256), dim3(256), 0, stream>>>(A, Mt, S, H, (l < 2) ? 1 : 0);
  }
}

// Round 2
// 160.505 us; speedup vs baseline: 1.1023x; 1.1023x over previous
//
#include <hip/hip_runtime.h>

typedef float  f32x4  __attribute__((ext_vector_type(4)));
typedef short  bf16x8 __attribute__((ext_vector_type(8)));

#define NN 2048
#define CC 64

__device__ __forceinline__ unsigned short f2bf(float f) {
  union { float f; unsigned u; } v; v.f = f;
  unsigned r = v.u + 0x7fffu + ((v.u >> 16) & 1u);
  return (unsigned short)(r >> 16);
}

// ---------- per-layer small linear: Mt = (H*Wm^T)^T (bf16), S = H*Ws^T + b (fp32) ----------
__global__ __launch_bounds__(256) void gcn_linear(
    const float* __restrict__ H, const float* __restrict__ Wm,
    const float* __restrict__ Ws, const float* __restrict__ bias,
    unsigned short* __restrict__ Mt, float* __restrict__ S)
{
  const int bid = blockIdx.x;
  const int b   = bid >> 5;          // 32 row-blocks per batch
  const int n0  = (bid & 31) << 6;   // 64 rows per block
  const int tid = threadIdx.x;

  __shared__ float4 Hl[1024];    // [row][c4] 64x16 float4
  __shared__ float4 Wm4[1024];   // [o][c4 ^ (o&15)] swizzled
  __shared__ float4 Ws4[1024];

  const float4* Hg  = reinterpret_cast<const float4*>(H + ((size_t)b * NN + n0) * CC);
  const float4* Wmg = reinterpret_cast<const float4*>(Wm);
  const float4* Wsg = reinterpret_cast<const float4*>(Ws);
#pragma unroll
  for (int i = 0; i < 4; ++i) {
    int f = tid + 256 * i;
    Hl[f] = Hg[f];
    int o = f >> 4, c4 = f & 15;
    int slot = (o << 4) | (c4 ^ (o & 15));
    Wm4[slot] = Wmg[f];
    Ws4[slot] = Wsg[f];
  }
  __syncthreads();

  const int o = tid & 63, wv = tid >> 6;
  float accm[16], accs[16];
#pragma unroll
  for (int p = 0; p < 16; ++p) { accm[p] = 0.f; accs[p] = 0.f; }

  for (int c4 = 0; c4 < 16; ++c4) {
    int slot = (o << 4) | (c4 ^ (o & 15));
    float4 wm  = Wm4[slot];
    float4 wsv = Ws4[slot];
#pragma unroll
    for (int p = 0; p < 16; ++p) {
      float4 h = Hl[((wv << 4) + p) * 16 + c4];   // broadcast within wave
      accm[p] += h.x * wm.x  + h.y * wm.y  + h.z * wm.z  + h.w * wm.w;
      accs[p] += h.x * wsv.x + h.y * wsv.y + h.z * wsv.z + h.w * wsv.w;
    }
  }

  const float bv = bias[o];
#pragma unroll
  for (int p = 0; p < 16; ++p) {
    int r = n0 + (wv << 4) + p;
    Mt[((size_t)b * CC + o) * NN + r] = f2bf(accm[p]);   // transposed store (bf16)
    S [((size_t)b * NN + r) * CC + o] = accs[p] + bv;    // coalesced fp32
  }
}

// shared epilogue: C/D layout col=lane&15, row=(lane>>4)*4+reg  [measured m89/m91]
__device__ __forceinline__ void gcn_epilogue(
    f32x4* acc, const float* __restrict__ S, float* __restrict__ Hout,
    int b, int i0, int w, int fr, int g, int relu)
{
  const int rbase = i0 + (w << 4) + (g << 2);
#pragma unroll
  for (int n = 0; n < 4; ++n) {
    const int col = (n << 4) | fr;
#pragma unroll
    for (int r = 0; r < 4; ++r) {
      const size_t idx = ((size_t)b * NN + (rbase + r)) * CC + col;
      float v = acc[n][r] + S[idx];
      if (relu) v = fmaxf(v, 0.f);
      Hout[idx] = v;
    }
  }
}

// ---------- layer-0 GEMM: fp32 A -> bf16 in reg, optional bf16-A side-store ----------
// No LDS, no barriers: wave-private register pipeline (A depth-2, B depth-1).
__global__ __launch_bounds__(256) void gcn_gemm_f32(
    const float* __restrict__ A, const unsigned short* __restrict__ Mt,
    const float* __restrict__ S, float* __restrict__ Hout,
    unsigned short* __restrict__ Abf, const int relu)
{
  const int bid = blockIdx.x;
  const int lg  = (bid & 7) * 32 + (bid >> 3);  // XCD x <-> batch x (L2 locality for Mt)
  const int b   = lg >> 5;
  const int i0  = (lg & 31) << 6;
  const int tid = threadIdx.x, lane = tid & 63, w = tid >> 6;
  const int fr = lane & 15, g = lane >> 4;
  const int row = i0 + (w << 4) + fr;

  const float* ap = A + ((size_t)b * NN + row) * NN + (g << 3);
  const unsigned short* Mb = Mt + (size_t)b * CC * NN + (size_t)fr * NN + (g << 3);
  const bool wr = (Abf != nullptr);
  unsigned short* abp = wr ? (Abf + ((size_t)b * NN + row) * NN + (g << 3)) : nullptr;

  f32x4 acc[4];
#pragma unroll
  for (int n = 0; n < 4; ++n) acc[n] = (f32x4){0.f, 0.f, 0.f, 0.f};

  float4 A0[4], A1[4];
  bf16x8 B0[8];
#pragma unroll
  for (int i = 0; i < 2; ++i) {
    A0[2*i+0] = *reinterpret_cast<const float4*>(ap + 32*i + 0);
    A0[2*i+1] = *reinterpret_cast<const float4*>(ap + 32*i + 4);
    A1[2*i+0] = *reinterpret_cast<const float4*>(ap + 64 + 32*i + 0);
    A1[2*i+1] = *reinterpret_cast<const float4*>(ap + 64 + 32*i + 4);
  }
#pragma unroll
  for (int kk = 0; kk < 2; ++kk)
#pragma unroll
    for (int n = 0; n < 4; ++n)
      B0[kk*4+n] = *reinterpret_cast<const bf16x8*>(Mb + (size_t)(n << 4) * NN + (kk << 5));

  for (int t = 0; t < 32; ++t) {
    float4 A2[4]; bf16x8 B1[8];
    if (t < 30) {
      const float* q = ap + (size_t)(t + 2) * 64;
#pragma unroll
      for (int i = 0; i < 2; ++i) {
        A2[2*i+0] = *reinterpret_cast<const float4*>(q + 32*i + 0);
        A2[2*i+1] = *reinterpret_cast<const float4*>(q + 32*i + 4);
      }
    }
    if (t < 31) {
      const unsigned short* mq = Mb + ((t + 1) << 6);
#pragma unroll
      for (int kk = 0; kk < 2; ++kk)
#pragma unroll
        for (int n = 0; n < 4; ++n)
          B1[kk*4+n] = *reinterpret_cast<const bf16x8*>(mq + (size_t)(n << 4) * NN + (kk << 5));
    }

    bf16x8 af[2];
#pragma unroll
    for (int kk = 0; kk < 2; ++kk) {
      af[kk][0] = (short)f2bf(A0[2*kk+0].x);
      af[kk][1] = (short)f2bf(A0[2*kk+0].y);
      af[kk][2] = (short)f2bf(A0[2*kk+0].z);
      af[kk][3] = (short)f2bf(A0[2*kk+0].w);
      af[kk][4] = (short)f2bf(A0[2*kk+1].x);
      af[kk][5] = (short)f2bf(A0[2*kk+1].y);
      af[kk][6] = (short)f2bf(A0[2*kk+1].z);
      af[kk][7] = (short)f2bf(A0[2*kk+1].w);
    }
    if (wr) {
      *reinterpret_cast<bf16x8*>(abp + t * 64)      = af[0];
      *reinterpret_cast<bf16x8*>(abp + t * 64 + 32) = af[1];
    }
#pragma unroll
    for (int kk = 0; kk < 2; ++kk)
#pragma unroll
      for (int n = 0; n < 4; ++n)
        acc[n] = __builtin_amdgcn_mfma_f32_16x16x32_bf16(af[kk], B0[kk*4+n], acc[n], 0, 0, 0);
#pragma unroll
    for (int i = 0; i < 4; ++i) { A0[i] = A1[i]; A1[i] = A2[i]; }
#pragma unroll
    for (int i = 0; i < 8; ++i) B0[i] = B1[i];
  }

  gcn_epilogue(acc, S, Hout, b, i0, w, fr, g, relu);
}

// ---------- layers 1..2 GEMM: bf16 A streamed straight to MFMA fragments ----------
__global__ __launch_bounds__(256) void gcn_gemm_bf16(
    const unsigned short* __restrict__ Abf, const unsigned short* __restrict__ Mt,
    const float* __restrict__ S, float* __restrict__ Hout, const int relu)
{
  const int bid = blockIdx.x;
  const int lg  = (bid & 7) * 32 + (bid >> 3);
  const int b   = lg >> 5;
  const int i0  = (lg & 31) << 6;
  const int tid = threadIdx.x, lane = tid & 63, w = tid >> 6;
  const int fr = lane & 15, g = lane >> 4;
  const int row = i0 + (w << 4) + fr;

  const unsigned short* ap = Abf + ((size_t)b * NN + row) * NN + (g << 3);
  const unsigned short* Mb = Mt + (size_t)b * CC * NN + (size_t)fr * NN + (g << 3);

  f32x4 acc[4];
#pragma unroll
  for (int n = 0; n < 4; ++n) acc[n] = (f32x4){0.f, 0.f, 0.f, 0.f};

  bf16x8 A0[2], A1[2], B0[8];
  A0[0] = *reinterpret_cast<const bf16x8*>(ap + 0);
  A0[1] = *reinterpret_cast<const bf16x8*>(ap + 32);
  A1[0] = *reinterpret_cast<const bf16x8*>(ap + 64);
  A1[1] = *reinterpret_cast<const bf16x8*>(ap + 96);
#pragma unroll
  for (int kk = 0; kk < 2; ++kk)
#pragma unroll
    for (int n = 0; n < 4; ++n)
      B0[kk*4+n] = *reinterpret_cast<const bf16x8*>(Mb + (size_t)(n << 4) * NN + (kk << 5));

  for (int t = 0; t < 32; ++t) {
    bf16x8 A2[2], B1[8];
    if (t < 30) {
      const unsigned short* q = ap + (size_t)(t + 2) * 64;
      A2[0] = *reinterpret_cast<const bf16x8*>(q + 0);
      A2[1] = *reinterpret_cast<const bf16x8*>(q + 32);
    }
    if (t < 31) {
      const unsigned short* mq = Mb + ((t + 1) << 6);
#pragma unroll
      for (int kk = 0; kk < 2; ++kk)
#pragma unroll
        for (int n = 0; n < 4; ++n)
          B1[kk*4+n] = *reinterpret_cast<const bf16x8*>(mq + (size_t)(n << 4) * NN + (kk << 5));
    }
#pragma unroll
    for (int kk = 0; kk < 2; ++kk)
#pragma unroll
      for (int n = 0; n < 4; ++n)
        acc[n] = __builtin_amdgcn_mfma_f32_16x16x32_bf16(A0[kk], B0[kk*4+n], acc[n], 0, 0, 0);
#pragma unroll
    for (int i = 0; i < 2; ++i) { A0[i] = A1[i]; A1[i] = A2[i]; }
#pragma unroll
    for (int i = 0; i < 8; ++i) B0[i] = B1[i];
  }

  gcn_epilogue(acc, S, Hout, b, i0, w, fr, g, relu);
}

extern "C" void kernel_launch(void* const* d_in, const int* in_sizes, int n_in,
                              void* d_out, int out_size, void* d_ws, size_t ws_size,
                              hipStream_t stream)
{
  const float* X = (const float*)d_in[0];
  const float* A = (const float*)d_in[1];
  unsigned short* Mt = (unsigned short*)d_ws;                       // 2 MiB bf16
  float* S = (float*)((char*)d_ws + (size_t)(2 * 1024 * 1024));     // 4 MiB fp32
  const size_t abf_off = (size_t)(6 * 1024 * 1024);
  const size_t need = abf_off + (size_t)8 * NN * NN * 2;            // +64 MiB bf16 A
  unsigned short* Abf = (ws_size >= need)
      ? (unsigned short*)((char*)d_ws + abf_off) : nullptr;
  float* H = (float*)d_out;                                         // ping-pong activations

  for (int l = 0; l < 3; ++l) {
    const float* Wm = (const float*)d_in[2 + 3 * l];
    const float* Ws = (const float*)d_in[3 + 3 * l];
    const float* bb = (const float*)d_in[4 + 3 * l];
    const float* src = (l == 0) ? X : H;
    const int relu = (l < 2) ? 1 : 0;
    gcn_linear<<<dim3(256), dim3(256), 0, stream>>>(src, Wm, Ws, bb, Mt, S);
    if (l == 0 || !Abf) {
      gcn_gemm_f32<<<dim3(256), dim3(256), 0, stream>>>(
          A, Mt, S, H, (l == 0) ? Abf : nullptr, relu);
    } else {
      gcn_gemm_bf16<<<dim3(256), dim3(256), 0, stream>>>(Abf, Mt, S, H, relu);
    }
  }
}